// Round 1
// baseline (227.209 us; speedup 1.0000x reference)
//
#include <hip/hip_runtime.h>

// out[m,k] = D*(w-1)*rowsum(t[m])  broadcast over k (K = D = 2048)
// Memory-bound: 128 MiB read + 128 MiB write -> roofline ~41 us @ 6.3 TB/s.

#define M_ROWS 16384
#define D_COLS 2048

__global__ __launch_bounds__(256)
void perm_equiv_rowsum_bcast(const float* __restrict__ t,
                             const float* __restrict__ w,
                             float* __restrict__ out) {
    const int row = blockIdx.x;
    const int tid = threadIdx.x;

    const float4* trow = reinterpret_cast<const float4*>(t + (size_t)row * D_COLS);
    // 2048 floats = 512 float4; 256 threads x 2 each, coalesced.
    float4 a = trow[tid];
    float4 b = trow[tid + 256];
    float s = (a.x + a.y) + (a.z + a.w) + (b.x + b.y) + (b.z + b.w);

    // wave-64 shuffle reduction
    #pragma unroll
    for (int off = 32; off > 0; off >>= 1)
        s += __shfl_down(s, off, 64);

    __shared__ float wave_sums[4];
    const int lane = tid & 63;
    const int wave = tid >> 6;
    if (lane == 0) wave_sums[wave] = s;
    __syncthreads();

    const float total = (wave_sums[0] + wave_sums[1]) + (wave_sums[2] + wave_sums[3]);
    const float v = (float)D_COLS * (w[0] - 1.0f) * total;

    float4 v4 = make_float4(v, v, v, v);
    float4* orow = reinterpret_cast<float4*>(out + (size_t)row * D_COLS);
    orow[tid] = v4;
    orow[tid + 256] = v4;
}

extern "C" void kernel_launch(void* const* d_in, const int* in_sizes, int n_in,
                              void* d_out, int out_size, void* d_ws, size_t ws_size,
                              hipStream_t stream) {
    const float* t = (const float*)d_in[0];
    const float* w = (const float*)d_in[1];
    float* out = (float*)d_out;
    perm_equiv_rowsum_bcast<<<M_ROWS, 256, 0, stream>>>(t, w, out);
}

// Round 3
// 222.802 us; speedup vs baseline: 1.0198x; 1.0198x over previous
//
#include <hip/hip_runtime.h>

// out[m,k] = D*(w-1)*rowsum(t[m]) broadcast over k (K = D = 2048).
// Memory-bound: 128 MiB read + 128 MiB write -> roofline ~41 us @ 6.3 TB/s.
//
// Structure: one wave (64 lanes) per row. 64 lanes x 8 float4 = 2048 floats.
// Wave-only shuffle reduction -> no LDS, no __syncthreads, waves fully
// independent. Nontemporal loads/stores: both streams are touch-once, so
// bypass L2/L3 retention. Native ext_vector_type float4 (HIP_vector_type
// is rejected by the nontemporal builtins).

#define M_ROWS 16384
#define D_COLS 2048
#define F4_PER_ROW (D_COLS / 4)   // 512
#define WAVES_PER_BLOCK 4
#define BLOCK_SIZE (WAVES_PER_BLOCK * 64)

typedef float vf4 __attribute__((ext_vector_type(4)));

__global__ __launch_bounds__(BLOCK_SIZE)
void perm_equiv_wave_row(const float* __restrict__ t,
                         const float* __restrict__ w,
                         float* __restrict__ out) {
    const int lane = threadIdx.x & 63;
    const int row  = blockIdx.x * WAVES_PER_BLOCK + (threadIdx.x >> 6);

    const vf4* trow = reinterpret_cast<const vf4*>(t) + (size_t)row * F4_PER_ROW;

    // 8 coalesced nontemporal 16B loads: lane i touches f4 index j*64 + i.
    vf4 v[8];
    #pragma unroll
    for (int j = 0; j < 8; ++j)
        v[j] = __builtin_nontemporal_load(trow + j * 64 + lane);

    float s = 0.0f;
    #pragma unroll
    for (int j = 0; j < 8; ++j)
        s += (v[j].x + v[j].y) + (v[j].z + v[j].w);

    // wave-64 butterfly: every lane ends with the full row sum.
    #pragma unroll
    for (int m = 32; m > 0; m >>= 1)
        s += __shfl_xor(s, m, 64);

    const float val = (float)D_COLS * (w[0] - 1.0f) * s;
    vf4 v4;
    v4.x = val; v4.y = val; v4.z = val; v4.w = val;

    vf4* orow = reinterpret_cast<vf4*>(out) + (size_t)row * F4_PER_ROW;
    #pragma unroll
    for (int j = 0; j < 8; ++j)
        __builtin_nontemporal_store(v4, orow + j * 64 + lane);
}

extern "C" void kernel_launch(void* const* d_in, const int* in_sizes, int n_in,
                              void* d_out, int out_size, void* d_ws, size_t ws_size,
                              hipStream_t stream) {
    const float* t = (const float*)d_in[0];
    const float* w = (const float*)d_in[1];
    float* out = (float*)d_out;
    perm_equiv_wave_row<<<M_ROWS / WAVES_PER_BLOCK, BLOCK_SIZE, 0, stream>>>(t, w, out);
}